// Round 3
// baseline (242.165 us; speedup 1.0000x reference)
//
#include <hip/hip_runtime.h>

// mean(|box5(x)-box5(y)|) = mean(|box5(x-y)|); separable 5x5 box, pad=4.
// B=64, H=W=512, out 516x516. R3: latency-bound fix — each wave owns a
// (img, 4-row output strip) and EXPLICITLY stages all 8 input rows of x and y
// into registers (32 independent float4 loads, ~8KB in flight per wave)
// before computing. Vertical rolling sum + in-register horizontal 5-tap with
// __shfl_up halo (layout verified absmax 0.0 in R2). Fused reduce+finalize.

#define TR      4
#define STRIPS  129             // 129*4 = 516
#define NBLOCKS ((STRIPS * 64) / 4)   // 2064 blocks x 4 waves = 8256 waves

__global__ __launch_bounds__(256) void box_loss_kernel(
    const float* __restrict__ x, const float* __restrict__ y,
    float* __restrict__ ws, float* __restrict__ out)
{
    __shared__ float wsum[4];

    const int lane  = threadIdx.x & 63;
    const int wid   = (blockIdx.x << 2) + (threadIdx.x >> 6);
    const int img   = wid / STRIPS;
    const int strip = wid - img * STRIPS;
    const int i0    = strip * TR;           // first output row

    const size_t base = (size_t)img * (512 * 512) + (size_t)(lane * 8);
    const float* xb = x + base;
    const float* yb = y + base;

    // ---- Stage ALL 8 input rows (i0-4 .. i0+3) of BOTH arrays up front.
    // 32 independent global_load_dwordx4 -> deep MLP, this is the point.
    float4 xs[8][2], ys[8][2];
    #pragma unroll
    for (int k = 0; k < 8; ++k) {
        const int r  = i0 - 4 + k;
        const int rc = min(max(r, 0), 511);
        const float4* xr = (const float4*)(xb + (size_t)rc * 512);
        const float4* yr = (const float4*)(yb + (size_t)rc * 512);
        xs[k][0] = xr[0]; xs[k][1] = xr[1];
        ys[k][0] = yr[0]; ys[k][1] = yr[1];
    }

    // ---- d rows (zero outside the image)
    float d[8][8];
    #pragma unroll
    for (int k = 0; k < 8; ++k) {
        const int r = i0 - 4 + k;
        const bool valid = (r >= 0) & (r < 512);
        d[k][0] = xs[k][0].x - ys[k][0].x;
        d[k][1] = xs[k][0].y - ys[k][0].y;
        d[k][2] = xs[k][0].z - ys[k][0].z;
        d[k][3] = xs[k][0].w - ys[k][0].w;
        d[k][4] = xs[k][1].x - ys[k][1].x;
        d[k][5] = xs[k][1].y - ys[k][1].y;
        d[k][6] = xs[k][1].z - ys[k][1].z;
        d[k][7] = xs[k][1].w - ys[k][1].w;
        #pragma unroll
        for (int j = 0; j < 8; ++j) d[k][j] = valid ? d[k][j] : 0.f;
    }

    // ---- vertical 5-row sums (rolling) + horizontal 5-tap + |.| accumulate
    float acc = 0.f;
    float v[8];
    #pragma unroll
    for (int j = 0; j < 8; ++j)
        v[j] = d[0][j] + d[1][j] + d[2][j] + d[3][j] + d[4][j];

    #pragma unroll
    for (int t = 0; t < TR; ++t) {
        if (t > 0) {
            #pragma unroll
            for (int j = 0; j < 8; ++j) v[j] += d[t + 4][j] - d[t - 1][j];
        }
        // halo: prev lane's v[4..7] = columns c0-4..c0-1
        float h0 = __shfl_up(v[4], 1, 64);
        float h1 = __shfl_up(v[5], 1, 64);
        float h2 = __shfl_up(v[6], 1, 64);
        float h3 = __shfl_up(v[7], 1, 64);
        if (lane == 0) { h0 = 0.f; h1 = 0.f; h2 = 0.f; h3 = 0.f; }

        float s = h0 + h1 + h2 + h3 + v[0];     // out col c0
        acc += fabsf(s);
        s += v[1] - h0;   acc += fabsf(s);
        s += v[2] - h1;   acc += fabsf(s);
        s += v[3] - h2;   acc += fabsf(s);
        s += v[4] - h3;   acc += fabsf(s);
        s += v[5] - v[0]; acc += fabsf(s);
        s += v[6] - v[1]; acc += fabsf(s);
        s += v[7] - v[2]; acc += fabsf(s);
        if (lane == 63) {                        // out cols 512..515 (right pad)
            float q = v[7];  acc += fabsf(q);
            q += v[6];       acc += fabsf(q);
            q += v[5];       acc += fabsf(q);
            q += v[4];       acc += fabsf(q);
        }
    }

    // ---- wave reduce, block reduce, global atomic, fused finalize
    #pragma unroll
    for (int off = 32; off > 0; off >>= 1)
        acc += __shfl_down(acc, off, 64);
    if (lane == 0) wsum[threadIdx.x >> 6] = acc;
    __syncthreads();

    if (threadIdx.x == 0) {
        float s = wsum[0] + wsum[1] + wsum[2] + wsum[3];
        atomicAdd(ws, s);
        __threadfence();
        unsigned* cnt = (unsigned*)(ws + 1);
        unsigned done = atomicAdd(cnt, 1u);
        if (done == (unsigned)(gridDim.x - 1)) {
            float total = atomicAdd(ws, 0.0f);   // coherent read of final sum
            out[0] = total * (1.0f / (25.0f * 64.0f * 516.0f * 516.0f));
        }
    }
}

extern "C" void kernel_launch(void* const* d_in, const int* in_sizes, int n_in,
                              void* d_out, int out_size, void* d_ws, size_t ws_size,
                              hipStream_t stream) {
    const float* x = (const float*)d_in[0];
    const float* y = (const float*)d_in[1];
    float* out = (float*)d_out;
    float* ws  = (float*)d_ws;

    hipMemsetAsync(ws, 0, 8, stream);   // ws[0]=sum, ws[1]=block counter

    box_loss_kernel<<<NBLOCKS, 256, 0, stream>>>(x, y, ws, out);
}

// Round 4
// 178.070 us; speedup vs baseline: 1.3599x; 1.3599x over previous
//
#include <hip/hip_runtime.h>

// mean(|box5(x)-box5(y)|) = mean(|box5(x-y)|); separable 5x5 box, pad=4.
// B=64, H=W=512, out 516x516.
// R4: (a) strip stagger per image (images are 1MB apart -> channel camping
// when all images read the same rows concurrently); (b) explicit depth-4
// load pipeline pinned with sched_barrier(0) so the compiler cannot sink
// the loads (R3 showed it re-serializes source-level staging: VGPR 72).

#define TR      12
#define STRIPS  43                    // 43*12 = 516
#define NBLOCKS ((STRIPS * 64) / 4)   // 688 blocks x 4 waves = 2752 waves
#define NROWS   (TR + 4)              // 16 input rows per strip

__global__ __launch_bounds__(256) void box_loss_kernel(
    const float* __restrict__ x, const float* __restrict__ y,
    float* __restrict__ ws, float* __restrict__ out)
{
    __shared__ float wsum[4];

    const int lane  = threadIdx.x & 63;
    const int wid   = (blockIdx.x << 2) + (threadIdx.x >> 6);
    const int img   = wid / STRIPS;
    const int s0    = wid - img * STRIPS;
    const int strip = (s0 + img * 17) % STRIPS;   // de-camp channels
    const int i0    = strip * TR;                 // first output row

    const size_t base = (size_t)img * (512 * 512) + (size_t)(lane * 8);
    const float* xb = x + base;
    const float* yb = y + base;

    // ---- depth-4 rotating load pipeline (4 stages x 4 float4 = 16 loads
    // in flight = 16 KB/wave). sched_barrier(0) pins issue points.
    float4 px[4][2], py[4][2];

    #pragma unroll
    for (int k = 0; k < 4; ++k) {
        const int r  = i0 - 4 + k;
        const int rc = min(max(r, 0), 511);
        const float4* xr = (const float4*)(xb + (size_t)rc * 512);
        const float4* yr = (const float4*)(yb + (size_t)rc * 512);
        px[k][0] = xr[0]; px[k][1] = xr[1];
        py[k][0] = yr[0]; py[k][1] = yr[1];
    }
    __builtin_amdgcn_sched_barrier(0);

    float hist[5][8], v[8];
    #pragma unroll
    for (int j = 0; j < 8; ++j) v[j] = 0.f;
    #pragma unroll
    for (int s = 0; s < 5; ++s)
        #pragma unroll
        for (int j = 0; j < 8; ++j) hist[s][j] = 0.f;

    float acc = 0.f;

    #pragma unroll
    for (int k = 0; k < NROWS; ++k) {
        const int st = k & 3;
        // consume stage st (waitcnt here is fine-grained: 12 newer loads stay in flight)
        float4 xa = px[st][0], xc = px[st][1];
        float4 ya = py[st][0], yc = py[st][1];

        // refill stage st with row k+4 (if any), pinned before compute
        if (k + 4 < NROWS) {
            const int r  = i0 - 4 + (k + 4);
            const int rc = min(max(r, 0), 511);
            const float4* xr = (const float4*)(xb + (size_t)rc * 512);
            const float4* yr = (const float4*)(yb + (size_t)rc * 512);
            px[st][0] = xr[0]; px[st][1] = xr[1];
            py[st][0] = yr[0]; py[st][1] = yr[1];
        }
        __builtin_amdgcn_sched_barrier(0);

        const int r = i0 - 4 + k;
        const bool valid = (r >= 0) & (r < 512);
        float d[8];
        d[0] = xa.x - ya.x; d[1] = xa.y - ya.y; d[2] = xa.z - ya.z; d[3] = xa.w - ya.w;
        d[4] = xc.x - yc.x; d[5] = xc.y - yc.y; d[6] = xc.z - yc.z; d[7] = xc.w - yc.w;
        #pragma unroll
        for (int j = 0; j < 8; ++j) d[j] = valid ? d[j] : 0.f;

        const int slot = k % 5;   // compile-time under full unroll
        #pragma unroll
        for (int j = 0; j < 8; ++j) {
            v[j] += d[j] - hist[slot][j];
            hist[slot][j] = d[j];
        }

        if (k >= 4) {             // output row i = i0 + (k-4)
            float h0 = __shfl_up(v[4], 1, 64);
            float h1 = __shfl_up(v[5], 1, 64);
            float h2 = __shfl_up(v[6], 1, 64);
            float h3 = __shfl_up(v[7], 1, 64);
            if (lane == 0) { h0 = 0.f; h1 = 0.f; h2 = 0.f; h3 = 0.f; }

            float s = h0 + h1 + h2 + h3 + v[0];   // out col c0
            acc += fabsf(s);
            s += v[1] - h0;   acc += fabsf(s);
            s += v[2] - h1;   acc += fabsf(s);
            s += v[3] - h2;   acc += fabsf(s);
            s += v[4] - h3;   acc += fabsf(s);
            s += v[5] - v[0]; acc += fabsf(s);
            s += v[6] - v[1]; acc += fabsf(s);
            s += v[7] - v[2]; acc += fabsf(s);
            if (lane == 63) {                     // out cols 512..515 (right pad)
                float q = v[7];  acc += fabsf(q);
                q += v[6];       acc += fabsf(q);
                q += v[5];       acc += fabsf(q);
                q += v[4];       acc += fabsf(q);
            }
        }
    }

    // ---- wave reduce, block reduce, global atomic, fused finalize
    #pragma unroll
    for (int off = 32; off > 0; off >>= 1)
        acc += __shfl_down(acc, off, 64);
    if (lane == 0) wsum[threadIdx.x >> 6] = acc;
    __syncthreads();

    if (threadIdx.x == 0) {
        float s = wsum[0] + wsum[1] + wsum[2] + wsum[3];
        atomicAdd(ws, s);
        __threadfence();
        unsigned* cnt = (unsigned*)(ws + 1);
        unsigned done = atomicAdd(cnt, 1u);
        if (done == (unsigned)(gridDim.x - 1)) {
            float total = atomicAdd(ws, 0.0f);    // coherent read of final sum
            out[0] = total * (1.0f / (25.0f * 64.0f * 516.0f * 516.0f));
        }
    }
}

extern "C" void kernel_launch(void* const* d_in, const int* in_sizes, int n_in,
                              void* d_out, int out_size, void* d_ws, size_t ws_size,
                              hipStream_t stream) {
    const float* x = (const float*)d_in[0];
    const float* y = (const float*)d_in[1];
    float* out = (float*)d_out;
    float* ws  = (float*)d_ws;

    hipMemsetAsync(ws, 0, 8, stream);   // ws[0]=sum, ws[1]=block counter

    box_loss_kernel<<<NBLOCKS, 256, 0, stream>>>(x, y, ws, out);
}